// Round 12
// baseline (49.692 us; speedup 1.0000x reference)
//
#include <hip/hip_runtime.h>

typedef float v2f __attribute__((ext_vector_type(2)));
typedef float v4f __attribute__((ext_vector_type(4)));

#define DEV static __device__ __forceinline__

// one fused dpp-add line for operand n
#define DL(n, ctrl) \
  "v_add_f32_dpp %" #n ", %" #n ", %" #n " " ctrl " row_mask:0xf bank_mask:0xf\n\t"

#define ST16(c) DL(0,c) DL(1,c) DL(2,c) DL(3,c) DL(4,c) DL(5,c) DL(6,c) DL(7,c) \
                DL(8,c) DL(9,c) DL(10,c) DL(11,c) DL(12,c) DL(13,c) DL(14,c) DL(15,c)
#define ST8(c)  DL(0,c) DL(1,c) DL(2,c) DL(3,c) DL(4,c) DL(5,c) DL(6,c) DL(7,c)

// Butterfly all-reduce over each 8-lane group (sample), interleaved chains.
// Stages: xor1, xor2, half-mirror (= xor4 once quads uniform).
// Interleave distance >> 2-cycle VALU->DPP hazard; s_nop 1 guards entry.
DEV void dpp3x16(float& r0, float& r1, float& r2, float& r3,
                 float& r4, float& r5, float& r6, float& r7,
                 float& r8, float& r9, float& r10, float& r11,
                 float& r12, float& r13, float& r14, float& r15) {
  asm("s_nop 1\n\t"
      ST16("quad_perm:[1,0,3,2]")
      ST16("quad_perm:[2,3,0,1]")
      ST16("row_half_mirror")
      : "+v"(r0), "+v"(r1), "+v"(r2), "+v"(r3),
        "+v"(r4), "+v"(r5), "+v"(r6), "+v"(r7),
        "+v"(r8), "+v"(r9), "+v"(r10), "+v"(r11),
        "+v"(r12), "+v"(r13), "+v"(r14), "+v"(r15));
}

DEV void dpp3x8(float& r0, float& r1, float& r2, float& r3,
                float& r4, float& r5, float& r6, float& r7) {
  asm("s_nop 1\n\t"
      ST8("quad_perm:[1,0,3,2]")
      ST8("quad_perm:[2,3,0,1]")
      ST8("row_half_mirror")
      : "+v"(r0), "+v"(r1), "+v"(r2), "+v"(r3),
        "+v"(r4), "+v"(r5), "+v"(r6), "+v"(r7));
}

// DPP move with bound_ctrl (OOB -> 0); compiler-managed hazards.
template<int CTRL>
DEV float dpp_movf(float v) {
  return __int_as_float(__builtin_amdgcn_update_dpp(
      0, __float_as_int(v), CTRL, 0xF, 0xF, true));
}

// gelu (logistic form): x * sigmoid(1.702 x); |err| <= 0.021 (budget 0.4125)
// z = -1.702*log2(e) = -2.4554672; 3 pk + 4 trans per pair
DEV v2f gelu2(v2f x) {
  v2f z  = x * -2.4554672f;
  v2f e  = { __builtin_amdgcn_exp2f(z.x), __builtin_amdgcn_exp2f(z.y) };
  v2f dn = e + 1.0f;
  v2f r  = { __builtin_amdgcn_rcpf(dn.x), __builtin_amdgcn_rcpf(dn.y) };
  return x * r;
}

__global__ void __launch_bounds__(256) gmlp_fused(
    const float* __restrict__ x,
    const float* __restrict__ ln1_g, const float* __restrict__ ln1_b,
    const float* __restrict__ W1, const float* __restrict__ b1,
    const float* __restrict__ sgu_g, const float* __restrict__ sgu_b,
    const float* __restrict__ conv_w, const float* __restrict__ conv_b,
    const float* __restrict__ W2, const float* __restrict__ b2,
    float* __restrict__ out, int nsamp)
{
  const int l  = threadIdx.x & 7;     // lane-in-sample: owns positions 4l..4l+3
  const int sg = threadIdx.x >> 3;    // sample within block (32 per block)
  const int p0 = l * 4;

  const int s = blockIdx.x * 32 + sg;
  if (s >= nsamp) return;

  const v4f g1q  = *(const v4f*)(ln1_g + p0);
  const v4f c1bq = *(const v4f*)(ln1_b + p0);
  const v4f g2q  = *(const v4f*)(sgu_g + p0);
  const v4f c2bq = *(const v4f*)(sgu_b + p0);

  // halo masks: left halo valid only if l>=1 (zero-pad), right if l<=6
  const float fl = (l >= 1) ? 1.0f : 0.0f;
  const float fr = (l <= 6) ? 1.0f : 0.0f;

  const float* xs = x + (size_t)s * 256 + p0;

  // ---- load x (8x dwordx4); x is the residual ----
  v4f xq[8];
#pragma unroll
  for (int c = 0; c < 8; ++c) xq[c] = *(const v4f*)(xs + c * 32);

  // ---- LN1: local pre-reduce then 3-stage DPP butterfly ----
  float r[16];
#pragma unroll
  for (int c = 0; c < 8; ++c) {
    v2f lo = { xq[c].x, xq[c].y }, hi = { xq[c].z, xq[c].w };
    v2f sp = lo + hi;
    v2f qp = lo * lo;
    qp = hi * hi + qp;
    r[c]     = sp.x + sp.y;
    r[8 + c] = qp.x + qp.y;
  }
  dpp3x16(r[0], r[1], r[2], r[3], r[4], r[5], r[6], r[7],
          r[8], r[9], r[10], r[11], r[12], r[13], r[14], r[15]);

  v2f h[8][2];
#pragma unroll
  for (int c = 0; c < 8; ++c) {
    float mu  = r[c] * 0.03125f;
    float var = __builtin_fmaf(r[8 + c], 0.03125f, -mu * mu);
    float rs  = __builtin_amdgcn_rsqf(var + 1e-5f);
    v2f A0 = v2f{ g1q.x, g1q.y } * rs, A1 = v2f{ g1q.z, g1q.w } * rs;
    v2f B0 = v2f{ c1bq.x, c1bq.y } - A0 * mu;
    v2f B1 = v2f{ c1bq.z, c1bq.w } - A1 * mu;
    h[c][0] = v2f{ xq[c].x, xq[c].y } * A0 + B0;
    h[c][1] = v2f{ xq[c].z, xq[c].w } * A1 + B1;
  }

  // ---- channel-mix matmul (8x8) + gelu ----
  v2f t[8][2];
#pragma unroll
  for (int o = 0; o < 8; ++o) {
    float bo = b1[o];
    v2f a0 = { bo, bo }, a1 = { bo, bo };
#pragma unroll
    for (int c = 0; c < 8; ++c) {
      float wv = W1[o * 8 + c];
      a0 = h[c][0] * wv + a0;
      a1 = h[c][1] * wv + a1;
    }
    t[o][0] = gelu2(a0);
    t[o][1] = gelu2(a1);
  }

  // ---- SGU LN2 on channels 4..7 ----
  float q[8];
#pragma unroll
  for (int c = 0; c < 4; ++c) {
    v2f sp = t[4 + c][0] + t[4 + c][1];
    v2f qp = t[4 + c][0] * t[4 + c][0];
    qp = t[4 + c][1] * t[4 + c][1] + qp;
    q[c]     = sp.x + sp.y;
    q[4 + c] = qp.x + qp.y;
  }
  dpp3x8(q[0], q[1], q[2], q[3], q[4], q[5], q[6], q[7]);

  // normalize all 4 v-channels upfront
  v2f vn[4][2];
#pragma unroll
  for (int c = 0; c < 4; ++c) {
    float mu  = q[c] * 0.03125f;
    float var = __builtin_fmaf(q[4 + c], 0.03125f, -mu * mu);
    float rs  = __builtin_amdgcn_rsqf(var + 1e-5f);
    v2f A0 = v2f{ g2q.x, g2q.y } * rs, A1 = v2f{ g2q.z, g2q.w } * rs;
    v2f B0 = v2f{ c2bq.x, c2bq.y } - A0 * mu;
    v2f B1 = v2f{ c2bq.z, c2bq.w } - A1 * mu;
    vn[c][0] = t[4 + c][0] * A0 + B0;
    vn[c][1] = t[4 + c][1] * A1 + B1;
  }

  // ---- conv: per-channel windows built on the fly, packed FMA ----
  v2f aA[4], aB[4];
#pragma unroll
  for (int o = 0; o < 4; ++o) {
    float cb = conv_b[o];
    aA[o] = v2f{ cb, cb };
    aB[o] = v2f{ cb, cb };
  }
#pragma unroll
  for (int c = 0; c < 4; ++c) {
    v2f v0 = vn[c][0], v1 = vn[c][1];
    float hL0 = dpp_movf<0x138>(v1.x) * fl;   // wave_shr1: lane l-1's v1
    float hL1 = dpp_movf<0x138>(v1.y) * fl;
    float hR0 = dpp_movf<0x130>(v0.x) * fr;   // wave_shl1: lane l+1's v0
    float hR1 = dpp_movf<0x130>(v0.y) * fr;
    v2f win[7];
    win[0] = v2f{ hL0, hL1 };
    win[1] = v2f{ hL1, v0.x };
    win[2] = v0;
    win[3] = v2f{ v0.y, v1.x };
    win[4] = v1;
    win[5] = v2f{ v1.y, hR0 };
    win[6] = v2f{ hR0, hR1 };
#pragma unroll
    for (int o = 0; o < 4; ++o) {
      const float* w = conv_w + (o * 4 + c) * 5;
#pragma unroll
      for (int j = 0; j < 5; ++j) {
        float wj = w[j];
        aA[o] = win[j]     * wj + aA[o];
        aB[o] = win[j + 2] * wj + aB[o];
      }
    }
  }
  // gate with u (= t[0..3])
  v2f gA[4], gB[4];
#pragma unroll
  for (int o = 0; o < 4; ++o) {
    gA[o] = t[o][0] * aA[o];
    gB[o] = t[o][1] * aB[o];
  }

  // ---- out matmul (4->8) + gelu + residual, plain dwordx4 store ----
  // (NT dropped this round: test whether L2/L3 write-caching beats HBM
  //  streaming in the steady-state replay loop)
  float* os = out + (size_t)s * 256 + p0;
#pragma unroll
  for (int o = 0; o < 8; ++o) {
    float bo = b2[o];
    v2f a0 = { bo, bo }, a1 = { bo, bo };
#pragma unroll
    for (int c = 0; c < 4; ++c) {
      float wv = W2[o * 4 + c];
      a0 = gA[c] * wv + a0;
      a1 = gB[c] * wv + a1;
    }
    v2f o0 = gelu2(a0) + v2f{ xq[o].x, xq[o].y };
    v2f o1 = gelu2(a1) + v2f{ xq[o].z, xq[o].w };
    v4f ov = { o0.x, o0.y, o1.x, o1.y };
    *(v4f*)(os + o * 32) = ov;
  }
}

extern "C" void kernel_launch(void* const* d_in, const int* in_sizes, int n_in,
                              void* d_out, int out_size, void* d_ws, size_t ws_size,
                              hipStream_t stream) {
  const float* x      = (const float*)d_in[0];
  const float* ln1_g  = (const float*)d_in[1];
  const float* ln1_b  = (const float*)d_in[2];
  const float* W1     = (const float*)d_in[3];
  const float* b1     = (const float*)d_in[4];
  const float* sgu_g  = (const float*)d_in[5];
  const float* sgu_b  = (const float*)d_in[6];
  const float* conv_w = (const float*)d_in[7];
  const float* conv_b = (const float*)d_in[8];
  const float* W2     = (const float*)d_in[9];
  const float* b2     = (const float*)d_in[10];
  float* out = (float*)d_out;

  int nsamp = in_sizes[0] / 256;        // 131072 samples of 8x32
  int nblocks = (nsamp + 31) / 32;      // single trip: 32 samples per block
  if (nblocks < 1) nblocks = 1;

  hipLaunchKernelGGL(gmlp_fused, dim3(nblocks), dim3(256), 0, stream,
                     x, ln1_g, ln1_b, W1, b1, sgu_g, sgu_b,
                     conv_w, conv_b, W2, b2, out, nsamp);
}

// Round 13
// 48.648 us; speedup vs baseline: 1.0215x; 1.0215x over previous
//
#include <hip/hip_runtime.h>

typedef float v2f __attribute__((ext_vector_type(2)));
typedef float v4f __attribute__((ext_vector_type(4)));

#define DEV static __device__ __forceinline__

// one fused dpp-add line for operand n
#define DL(n, ctrl) \
  "v_add_f32_dpp %" #n ", %" #n ", %" #n " " ctrl " row_mask:0xf bank_mask:0xf\n\t"

#define ST16(c) DL(0,c) DL(1,c) DL(2,c) DL(3,c) DL(4,c) DL(5,c) DL(6,c) DL(7,c) \
                DL(8,c) DL(9,c) DL(10,c) DL(11,c) DL(12,c) DL(13,c) DL(14,c) DL(15,c)
#define ST8(c)  DL(0,c) DL(1,c) DL(2,c) DL(3,c) DL(4,c) DL(5,c) DL(6,c) DL(7,c)

// Butterfly all-reduce over each 8-lane group (sample), interleaved chains.
// Stages: xor1, xor2, half-mirror (= xor4 once quads uniform).
// Interleave distance >> 2-cycle VALU->DPP hazard; s_nop 1 guards entry.
DEV void dpp3x16(float& r0, float& r1, float& r2, float& r3,
                 float& r4, float& r5, float& r6, float& r7,
                 float& r8, float& r9, float& r10, float& r11,
                 float& r12, float& r13, float& r14, float& r15) {
  asm("s_nop 1\n\t"
      ST16("quad_perm:[1,0,3,2]")
      ST16("quad_perm:[2,3,0,1]")
      ST16("row_half_mirror")
      : "+v"(r0), "+v"(r1), "+v"(r2), "+v"(r3),
        "+v"(r4), "+v"(r5), "+v"(r6), "+v"(r7),
        "+v"(r8), "+v"(r9), "+v"(r10), "+v"(r11),
        "+v"(r12), "+v"(r13), "+v"(r14), "+v"(r15));
}

DEV void dpp3x8(float& r0, float& r1, float& r2, float& r3,
                float& r4, float& r5, float& r6, float& r7) {
  asm("s_nop 1\n\t"
      ST8("quad_perm:[1,0,3,2]")
      ST8("quad_perm:[2,3,0,1]")
      ST8("row_half_mirror")
      : "+v"(r0), "+v"(r1), "+v"(r2), "+v"(r3),
        "+v"(r4), "+v"(r5), "+v"(r6), "+v"(r7));
}

// DPP move with bound_ctrl (OOB -> 0); compiler-managed hazards.
template<int CTRL>
DEV float dpp_movf(float v) {
  return __int_as_float(__builtin_amdgcn_update_dpp(
      0, __float_as_int(v), CTRL, 0xF, 0xF, true));
}

// gelu (logistic form): x * sigmoid(1.702 x); |err| <= 0.021 (budget 0.4125)
// z = -1.702*log2(e) = -2.4554672; 3 pk + 4 trans per pair
DEV v2f gelu2(v2f x) {
  v2f z  = x * -2.4554672f;
  v2f e  = { __builtin_amdgcn_exp2f(z.x), __builtin_amdgcn_exp2f(z.y) };
  v2f dn = e + 1.0f;
  v2f r  = { __builtin_amdgcn_rcpf(dn.x), __builtin_amdgcn_rcpf(dn.y) };
  return x * r;
}

__global__ void __launch_bounds__(256) gmlp_fused(
    const float* __restrict__ x,
    const float* __restrict__ ln1_g, const float* __restrict__ ln1_b,
    const float* __restrict__ W1, const float* __restrict__ b1,
    const float* __restrict__ sgu_g, const float* __restrict__ sgu_b,
    const float* __restrict__ conv_w, const float* __restrict__ conv_b,
    const float* __restrict__ W2, const float* __restrict__ b2,
    float* __restrict__ out, int nsamp)
{
  const int l  = threadIdx.x & 7;     // lane-in-sample: owns positions 4l..4l+3
  const int sg = threadIdx.x >> 3;    // sample within block (32 per block)
  const int p0 = l * 4;

  const int s = blockIdx.x * 32 + sg;
  if (s >= nsamp) return;

  const v4f g1q  = *(const v4f*)(ln1_g + p0);
  const v4f c1bq = *(const v4f*)(ln1_b + p0);
  const v4f g2q  = *(const v4f*)(sgu_g + p0);
  const v4f c2bq = *(const v4f*)(sgu_b + p0);

  // halo masks: left halo valid only if l>=1 (zero-pad), right if l<=6
  const float fl = (l >= 1) ? 1.0f : 0.0f;
  const float fr = (l <= 6) ? 1.0f : 0.0f;

  const float* xs = x + (size_t)s * 256 + p0;

  // ---- load x (8x dwordx4); x is the residual ----
  v4f xq[8];
#pragma unroll
  for (int c = 0; c < 8; ++c) xq[c] = *(const v4f*)(xs + c * 32);

  // ---- LN1: local pre-reduce then 3-stage DPP butterfly ----
  float r[16];
#pragma unroll
  for (int c = 0; c < 8; ++c) {
    v2f lo = { xq[c].x, xq[c].y }, hi = { xq[c].z, xq[c].w };
    v2f sp = lo + hi;
    v2f qp = lo * lo;
    qp = hi * hi + qp;
    r[c]     = sp.x + sp.y;
    r[8 + c] = qp.x + qp.y;
  }
  dpp3x16(r[0], r[1], r[2], r[3], r[4], r[5], r[6], r[7],
          r[8], r[9], r[10], r[11], r[12], r[13], r[14], r[15]);

  v2f h[8][2];
#pragma unroll
  for (int c = 0; c < 8; ++c) {
    float mu  = r[c] * 0.03125f;
    float var = __builtin_fmaf(r[8 + c], 0.03125f, -mu * mu);
    float rs  = __builtin_amdgcn_rsqf(var + 1e-5f);
    v2f A0 = v2f{ g1q.x, g1q.y } * rs, A1 = v2f{ g1q.z, g1q.w } * rs;
    v2f B0 = v2f{ c1bq.x, c1bq.y } - A0 * mu;
    v2f B1 = v2f{ c1bq.z, c1bq.w } - A1 * mu;
    h[c][0] = v2f{ xq[c].x, xq[c].y } * A0 + B0;
    h[c][1] = v2f{ xq[c].z, xq[c].w } * A1 + B1;
  }

  // ---- channel-mix matmul (8x8) + gelu ----
  v2f t[8][2];
#pragma unroll
  for (int o = 0; o < 8; ++o) {
    float bo = b1[o];
    v2f a0 = { bo, bo }, a1 = { bo, bo };
#pragma unroll
    for (int c = 0; c < 8; ++c) {
      float wv = W1[o * 8 + c];
      a0 = h[c][0] * wv + a0;
      a1 = h[c][1] * wv + a1;
    }
    t[o][0] = gelu2(a0);
    t[o][1] = gelu2(a1);
  }

  // ---- SGU LN2 on channels 4..7 ----
  float q[8];
#pragma unroll
  for (int c = 0; c < 4; ++c) {
    v2f sp = t[4 + c][0] + t[4 + c][1];
    v2f qp = t[4 + c][0] * t[4 + c][0];
    qp = t[4 + c][1] * t[4 + c][1] + qp;
    q[c]     = sp.x + sp.y;
    q[4 + c] = qp.x + qp.y;
  }
  dpp3x8(q[0], q[1], q[2], q[3], q[4], q[5], q[6], q[7]);

  // normalize all 4 v-channels upfront
  v2f vn[4][2];
#pragma unroll
  for (int c = 0; c < 4; ++c) {
    float mu  = q[c] * 0.03125f;
    float var = __builtin_fmaf(q[4 + c], 0.03125f, -mu * mu);
    float rs  = __builtin_amdgcn_rsqf(var + 1e-5f);
    v2f A0 = v2f{ g2q.x, g2q.y } * rs, A1 = v2f{ g2q.z, g2q.w } * rs;
    v2f B0 = v2f{ c2bq.x, c2bq.y } - A0 * mu;
    v2f B1 = v2f{ c2bq.z, c2bq.w } - A1 * mu;
    vn[c][0] = t[4 + c][0] * A0 + B0;
    vn[c][1] = t[4 + c][1] * A1 + B1;
  }

  // ---- conv: per-channel windows built on the fly, packed FMA ----
  v2f aA[4], aB[4];
#pragma unroll
  for (int o = 0; o < 4; ++o) {
    float cb = conv_b[o];
    aA[o] = v2f{ cb, cb };
    aB[o] = v2f{ cb, cb };
  }
#pragma unroll
  for (int c = 0; c < 4; ++c) {
    v2f v0 = vn[c][0], v1 = vn[c][1];
    float hL0 = dpp_movf<0x138>(v1.x) * fl;   // wave_shr1: lane l-1's v1
    float hL1 = dpp_movf<0x138>(v1.y) * fl;
    float hR0 = dpp_movf<0x130>(v0.x) * fr;   // wave_shl1: lane l+1's v0
    float hR1 = dpp_movf<0x130>(v0.y) * fr;
    v2f win[7];
    win[0] = v2f{ hL0, hL1 };
    win[1] = v2f{ hL1, v0.x };
    win[2] = v0;
    win[3] = v2f{ v0.y, v1.x };
    win[4] = v1;
    win[5] = v2f{ v1.y, hR0 };
    win[6] = v2f{ hR0, hR1 };
#pragma unroll
    for (int o = 0; o < 4; ++o) {
      const float* w = conv_w + (o * 4 + c) * 5;
#pragma unroll
      for (int j = 0; j < 5; ++j) {
        float wj = w[j];
        aA[o] = win[j]     * wj + aA[o];
        aB[o] = win[j + 2] * wj + aB[o];
      }
    }
  }
  // gate with u (= t[0..3])
  v2f gA[4], gB[4];
#pragma unroll
  for (int o = 0; o < 4; ++o) {
    gA[o] = t[o][0] * aA[o];
    gB[o] = t[o][1] * aB[o];
  }

  // ---- out matmul (4->8) + gelu + residual, NT dwordx4 store ----
  float* os = out + (size_t)s * 256 + p0;
#pragma unroll
  for (int o = 0; o < 8; ++o) {
    float bo = b2[o];
    v2f a0 = { bo, bo }, a1 = { bo, bo };
#pragma unroll
    for (int c = 0; c < 4; ++c) {
      float wv = W2[o * 4 + c];
      a0 = gA[c] * wv + a0;
      a1 = gB[c] * wv + a1;
    }
    v2f o0 = gelu2(a0) + v2f{ xq[o].x, xq[o].y };
    v2f o1 = gelu2(a1) + v2f{ xq[o].z, xq[o].w };
    v4f ov = { o0.x, o0.y, o1.x, o1.y };
    __builtin_nontemporal_store(ov, (v4f*)(os + o * 32));
  }
}

extern "C" void kernel_launch(void* const* d_in, const int* in_sizes, int n_in,
                              void* d_out, int out_size, void* d_ws, size_t ws_size,
                              hipStream_t stream) {
  const float* x      = (const float*)d_in[0];
  const float* ln1_g  = (const float*)d_in[1];
  const float* ln1_b  = (const float*)d_in[2];
  const float* W1     = (const float*)d_in[3];
  const float* b1     = (const float*)d_in[4];
  const float* sgu_g  = (const float*)d_in[5];
  const float* sgu_b  = (const float*)d_in[6];
  const float* conv_w = (const float*)d_in[7];
  const float* conv_b = (const float*)d_in[8];
  const float* W2     = (const float*)d_in[9];
  const float* b2     = (const float*)d_in[10];
  float* out = (float*)d_out;

  int nsamp = in_sizes[0] / 256;        // 131072 samples of 8x32
  int nblocks = (nsamp + 31) / 32;      // single trip: 32 samples per block
  if (nblocks < 1) nblocks = 1;

  hipLaunchKernelGGL(gmlp_fused, dim3(nblocks), dim3(256), 0, stream,
                     x, ln1_g, ln1_b, W1, b1, sgu_g, sgu_b,
                     conv_w, conv_b, W2, b2, out, nsamp);
}